// Round 3
// baseline (543.958 us; speedup 1.0000x reference)
//
#include <hip/hip_runtime.h>

#define NCONN 21

typedef float f4 __attribute__((ext_vector_type(4)));

__device__ __forceinline__ float acos_poly(float c) {
    // clamp; fminf first so NaN -> 1 -> acos = 0 (matches ref NaN->0)
    c = fmaxf(fminf(c, 1.0f), -1.0f);
    float t = fabsf(c);
    float s = sqrtf(1.0f - t);
    // Abramowitz & Stegun 4.4.45, |err| <= 6.7e-5
    float p = fmaf(t, -0.0187293f, 0.0742610f);
    p = fmaf(t, p, -0.2121144f);
    p = fmaf(t, p, 1.5707288f);
    float r = s * p;
    return (c >= 0.0f) ? r : (3.14159265358979f - r);
}

// ============================ k1: normalize -> transposed planes =============
// Stages 256 batches (rotated LDS rows), normalizes, writes 60 planes
// ws[q*B + b] = u_{e}[c] with q = 3*(e-1)+c, e = 1..20.
// Regular (cached) stores: 63 MB stays dirty in L2/L3 for k2 to read back.
__global__ __launch_bounds__(256, 2) void k1_planes(const float* __restrict__ in,
                                                    float* __restrict__ ws, int B) {
    __shared__ float lds[256 * 64];
    const int tid = threadIdx.x;
    const long long blockBatch = (long long)blockIdx.x * 256;

    const long long gBase4 = blockBatch * 63 / 4;
    const float4* in4 = (const float4*)in;
    #pragma unroll
    for (int it = 0; it < 16; ++it) {
        int t4 = tid + it * 256;
        if (t4 < 4032) {                       // 256*63/4
            float4 v = in4[gBase4 + t4];
            float vals[4] = {v.x, v.y, v.z, v.w};
            int f = 4 * t4;
            #pragma unroll
            for (int q = 0; q < 4; ++q) {
                int f2 = f + q;
                int r  = f2 / 63;              // magic-mul
                int c  = f2 - r * 63;
                lds[r * 64 + ((c + (r >> 2)) & 63)] = vals[q];
            }
        }
    }
    __syncthreads();

    {   // normalize own row in place
        float* row = lds + tid * 64;
        const int rot = tid >> 2;
        const float p0x = row[(0 + rot) & 63];
        const float p0y = row[(1 + rot) & 63];
        const float p0z = row[(2 + rot) & 63];
        #pragma unroll
        for (int e = 1; e < NCONN; ++e) {
            const int s0 = (3 * e + 0 + rot) & 63;
            const int s1 = (3 * e + 1 + rot) & 63;
            const int s2 = (3 * e + 2 + rot) & 63;
            float vx = row[s0] - p0x;
            float vy = row[s1] - p0y;
            float vz = row[s2] - p0z;
            float d  = fmaf(vx, vx, fmaf(vy, vy, vz * vz));
            float rr = rsqrtf(d);
            row[s0] = vx * rr;
            row[s1] = vy * rr;
            row[s2] = vz * rr;
        }
    }
    __syncthreads();

    // plane writes: wave w handles planes q = w, w+4, ...
    const int l = tid & 63, w = tid >> 6;
    const int rowb = 4 * l;                    // rows rowb..rowb+3 have rot == l
    for (int q = w; q < 60; q += 4) {
        f4 val;
        #pragma unroll
        for (int k = 0; k < 4; ++k)            // in-row index = 3e+c = q+3
            val[k] = lds[(rowb + k) * 64 + ((q + 3 + l) & 63)];
        *(f4*)(ws + (size_t)q * B + blockBatch + rowb) = val;
    }
}

// ============================ k2: row-pair streaming =========================
// Wave W: unit = W%11, span = W/11 (1024 batches). unit 10 -> i=0 zeros row.
// unit u<10 -> rows i0=2u+1, i1=2u+2. Per 256-batch chunk: 6 f4 u_i loads,
// then per j: 3 f4 plane loads, 8 angles, 2 NT f4 stores. Each output stream
// receives 4 KB sequential from one wave (vs 1 KB one-shot before); concurrent
// streams drop ~80x.
#define SPAN 1024
__global__ __launch_bounds__(256) void k2_rows(const float* __restrict__ ws,
                                               float* __restrict__ out, int B) {
    const int tid = threadIdx.x;
    const int l = tid & 63;
    const int W = blockIdx.x * 4 + (tid >> 6);
    const int unit = W % 11;
    const int sp = W / 11;
    const long long b0 = (long long)sp * SPAN;
    const size_t sB = (size_t)B;
    const f4 z4 = {0.f, 0.f, 0.f, 0.f};

    for (int ch = 0; ch < SPAN / 256; ++ch) {
        const long long lb = b0 + ch * 256 + 4 * l;     // lane's 4 batches
        if (unit == 10) {
            // i = 0 row: 21 zero streams
            for (int j = 0; j < NCONN; ++j)
                __builtin_nontemporal_store(z4, (f4*)(out + (size_t)j * sB + lb));
        } else {
            const int i0 = 2 * unit + 1, i1 = i0 + 1;
            const float* pw = ws + lb;
            const f4 ax = *(const f4*)(pw + (size_t)(3 * (i0 - 1) + 0) * sB);
            const f4 ay = *(const f4*)(pw + (size_t)(3 * (i0 - 1) + 1) * sB);
            const f4 az = *(const f4*)(pw + (size_t)(3 * (i0 - 1) + 2) * sB);
            const f4 bx = *(const f4*)(pw + (size_t)(3 * (i1 - 1) + 0) * sB);
            const f4 by = *(const f4*)(pw + (size_t)(3 * (i1 - 1) + 1) * sB);
            const f4 bz = *(const f4*)(pw + (size_t)(3 * (i1 - 1) + 2) * sB);
            // j = 0 columns: zeros
            __builtin_nontemporal_store(z4, (f4*)(out + (size_t)(i0 * NCONN) * sB + lb));
            __builtin_nontemporal_store(z4, (f4*)(out + (size_t)(i1 * NCONN) * sB + lb));
            for (int j = 1; j < NCONN; ++j) {
                const f4 jx = *(const f4*)(pw + (size_t)(3 * (j - 1) + 0) * sB);
                const f4 jy = *(const f4*)(pw + (size_t)(3 * (j - 1) + 1) * sB);
                const f4 jz = *(const f4*)(pw + (size_t)(3 * (j - 1) + 2) * sB);
                f4 a0, a1;
                #pragma unroll
                for (int k = 0; k < 4; ++k) {
                    a0[k] = acos_poly(fmaf(ax[k], jx[k], fmaf(ay[k], jy[k], az[k] * jz[k])));
                    a1[k] = acos_poly(fmaf(bx[k], jx[k], fmaf(by[k], jy[k], bz[k] * jz[k])));
                }
                __builtin_nontemporal_store(a0, (f4*)(out + (size_t)(i0 * NCONN + j) * sB + lb));
                __builtin_nontemporal_store(a1, (f4*)(out + (size_t)(i1 * NCONN + j) * sB + lb));
            }
        }
    }
}

// ============================ fallback: proven R2 kernel =====================
#define FTPB 512
#define FBPB 256
__global__ __launch_bounds__(FTPB, 4) void pv_fallback(const float* __restrict__ in,
                                                       float* __restrict__ out,
                                                       int B) {
    __shared__ float lds[FBPB * 64];
    const int tid = threadIdx.x;
    const long long blockBatch = (long long)blockIdx.x * FBPB;

    const long long gBase4 = blockBatch * 63 / 4;
    const long long totalF4 = ((long long)B * 63) >> 2;
    const float4* in4 = (const float4*)in;
    #pragma unroll
    for (int it = 0; it < 8; ++it) {
        int t4 = tid + it * FTPB;
        if (t4 < (FBPB * 63) / 4) {
            long long g4 = gBase4 + t4;
            if (g4 < totalF4) {
                float4 v = in4[g4];
                float vals[4] = {v.x, v.y, v.z, v.w};
                int f = 4 * t4;
                #pragma unroll
                for (int q = 0; q < 4; ++q) {
                    int f2 = f + q;
                    int r  = f2 / 63;
                    int c  = f2 - r * 63;
                    lds[r * 64 + ((c + (r >> 2)) & 63)] = vals[q];
                }
            }
        }
    }
    __syncthreads();

    if (tid < FBPB && blockBatch + tid < B) {
        float* row = lds + tid * 64;
        const int rot = tid >> 2;
        const float p0x = row[(0 + rot) & 63];
        const float p0y = row[(1 + rot) & 63];
        const float p0z = row[(2 + rot) & 63];
        #pragma unroll
        for (int e = 1; e < NCONN; ++e) {
            const int s0 = (3 * e + 0 + rot) & 63;
            const int s1 = (3 * e + 1 + rot) & 63;
            const int s2 = (3 * e + 2 + rot) & 63;
            float vx = row[s0] - p0x;
            float vy = row[s1] - p0y;
            float vz = row[s2] - p0z;
            float d  = fmaf(vx, vx, fmaf(vy, vy, vz * vz));
            float rr = rsqrtf(d);
            row[s0] = vx * rr;
            row[s1] = vy * rr;
            row[s2] = vz * rr;
        }
    }
    __syncthreads();

    const int l = tid & 63;
    const int w = tid >> 6;
    const int rowb = 4 * l;
    const long long remLL = B - blockBatch;
    const int rem = (int)(remLL < FBPB ? remLL : (long long)FBPB);
    const bool fullv = (rowb + 4 <= rem);
    float* op = out + blockBatch + rowb;
    const size_t sB = (size_t)B;

    {
        const f4 z4 = {0.f, 0.f, 0.f, 0.f};
        for (int idx = w; idx < 41; idx += 8) {
            const int p = (idx < 21) ? idx : (idx - 20) * NCONN;
            float* dst = op + (size_t)p * sB;
            if (fullv) __builtin_nontemporal_store(z4, (f4*)dst);
            else for (int k = 0; rowb + k < rem; ++k) dst[k] = 0.0f;
        }
    }

    for (int idx = w; idx < 400; idx += 8) {
        const int i = idx / 20 + 1;
        const int j = idx - (i - 1) * 20 + 1;
        f4 ang;
        #pragma unroll
        for (int k = 0; k < 4; ++k) {
            const float* row = lds + (rowb + k) * 64;
            const float uix = row[(3 * i + 0 + l) & 63];
            const float uiy = row[(3 * i + 1 + l) & 63];
            const float uiz = row[(3 * i + 2 + l) & 63];
            const float ujx = row[(3 * j + 0 + l) & 63];
            const float ujy = row[(3 * j + 1 + l) & 63];
            const float ujz = row[(3 * j + 2 + l) & 63];
            ang[k] = acos_poly(fmaf(uix, ujx, fmaf(uiy, ujy, uiz * ujz)));
        }
        float* dst = op + (size_t)(i * NCONN + j) * sB;
        if (fullv) __builtin_nontemporal_store(ang, (f4*)dst);
        else for (int k = 0; rowb + k < rem; ++k) dst[k] = ang[k];
    }
}

extern "C" void kernel_launch(void* const* d_in, const int* in_sizes, int n_in,
                              void* d_out, int out_size, void* d_ws, size_t ws_size,
                              hipStream_t stream) {
    const float* in = (const float*)d_in[0];
    float* out = (float*)d_out;
    const int B = in_sizes[0] / (NCONN * 3);   // 262144
    const size_t needWS = (size_t)60 * (size_t)B * sizeof(float);   // 62.9 MB

    if (ws_size >= needWS && (B % 4096) == 0) {
        float* ws = (float*)d_ws;
        hipLaunchKernelGGL(k1_planes, dim3(B / 256), dim3(256), 0, stream, in, ws, B);
        const int waves = 11 * (B / SPAN);     // 2816, divisible by 4
        hipLaunchKernelGGL(k2_rows, dim3(waves / 4), dim3(256), 0, stream, ws, out, B);
    } else {
        const int grid = (B + FBPB - 1) / FBPB;
        hipLaunchKernelGGL(pv_fallback, dim3(grid), dim3(FTPB), 0, stream, in, out, B);
    }
}

// Round 4
// 534.668 us; speedup vs baseline: 1.0174x; 1.0174x over previous
//
#include <hip/hip_runtime.h>

#define NCONN 21

typedef float f4 __attribute__((ext_vector_type(4)));

__device__ __forceinline__ float acos_poly(float c) {
    // clamp; fminf first so NaN -> 1 -> acos = 0 (matches ref NaN->0)
    c = fmaxf(fminf(c, 1.0f), -1.0f);
    float t = fabsf(c);
    float s = sqrtf(1.0f - t);
    // Abramowitz & Stegun 4.4.45, |err| <= 6.7e-5
    float p = fmaf(t, -0.0187293f, 0.0742610f);
    p = fmaf(t, p, -0.2121144f);
    p = fmaf(t, p, 1.5707288f);
    float r = s * p;
    return (c >= 0.0f) ? r : (3.14159265358979f - r);
}

// ============================ k1: normalize -> transposed planes =============
// ws[q*B + b] = u_e[c], q = 3*(e-1)+c, e = 1..20.  (proven in R3)
__global__ __launch_bounds__(256, 2) void k1_planes(const float* __restrict__ in,
                                                    float* __restrict__ ws, int B) {
    __shared__ float lds[256 * 64];
    const int tid = threadIdx.x;
    const long long blockBatch = (long long)blockIdx.x * 256;

    const long long gBase4 = blockBatch * 63 / 4;
    const float4* in4 = (const float4*)in;
    #pragma unroll
    for (int it = 0; it < 16; ++it) {
        int t4 = tid + it * 256;
        if (t4 < 4032) {                       // 256*63/4
            float4 v = in4[gBase4 + t4];
            float vals[4] = {v.x, v.y, v.z, v.w};
            int f = 4 * t4;
            #pragma unroll
            for (int q = 0; q < 4; ++q) {
                int f2 = f + q;
                int r  = f2 / 63;              // magic-mul
                int c  = f2 - r * 63;
                lds[r * 64 + ((c + (r >> 2)) & 63)] = vals[q];
            }
        }
    }
    __syncthreads();

    {   // normalize own row in place
        float* row = lds + tid * 64;
        const int rot = tid >> 2;
        const float p0x = row[(0 + rot) & 63];
        const float p0y = row[(1 + rot) & 63];
        const float p0z = row[(2 + rot) & 63];
        #pragma unroll
        for (int e = 1; e < NCONN; ++e) {
            const int s0 = (3 * e + 0 + rot) & 63;
            const int s1 = (3 * e + 1 + rot) & 63;
            const int s2 = (3 * e + 2 + rot) & 63;
            float vx = row[s0] - p0x;
            float vy = row[s1] - p0y;
            float vz = row[s2] - p0z;
            float d  = fmaf(vx, vx, fmaf(vy, vy, vz * vz));
            float rr = rsqrtf(d);
            row[s0] = vx * rr;
            row[s1] = vy * rr;
            row[s2] = vz * rr;
        }
    }
    __syncthreads();

    const int l = tid & 63, w = tid >> 6;
    const int rowb = 4 * l;                    // rows rowb..rowb+3 have rot == l
    for (int q = w; q < 60; q += 4) {
        f4 val;
        #pragma unroll
        for (int k = 0; k < 4; ++k)
            val[k] = lds[(rowb + k) * 64 + ((q + 3 + l) & 63)];
        *(f4*)(ws + (size_t)q * B + blockBatch + rowb) = val;
    }
}

// ============================ k2: plane-sweep ================================
// Grid = 6 groups x NS spans (group-major). Group g<5 owns i = 4g+1..4g+4;
// group 5 writes the i=0 zero planes. Span s covers batches [s*1024, s*1024+1024);
// thread t owns batches s*1024+4t.. (one f4). No LDS; u_i lives in 48 VGPRs.
// All blocks sweep j in the same order with identical work -> at any instant the
// device writes ~24 planes DENSELY over their full extents (all spans resident),
// mimicking the fill kernel's linear address stream; u_j reads (same 3 planes
// device-wide per step) hit L2/L3.
__global__ __launch_bounds__(256) void k2_sweep(const float* __restrict__ ws,
                                                float* __restrict__ out, int B) {
    const int NS = B >> 10;                    // spans
    const int g = blockIdx.x / NS;
    const int s = blockIdx.x - g * NS;
    const int tid = threadIdx.x;
    const long long b0 = ((long long)s << 10) + 4 * tid;
    const size_t sB = (size_t)B;
    float* po = out + b0;
    const f4 z4 = {0.f, 0.f, 0.f, 0.f};

    if (g == 5) {                              // i = 0 row: planes 0..20 are zeros
        #pragma unroll
        for (int p = 0; p < NCONN; ++p)
            __builtin_nontemporal_store(z4, (f4*)(po + (size_t)p * sB));
        return;
    }

    const float* pw = ws + b0;
    f4 ix[4], iy[4], iz[4];
    #pragma unroll
    for (int k = 0; k < 4; ++k) {
        const int q = 3 * (4 * g + k);         // 3*(i-1), i = 4g+1+k
        ix[k] = *(const f4*)(pw + (size_t)(q + 0) * sB);
        iy[k] = *(const f4*)(pw + (size_t)(q + 1) * sB);
        iz[k] = *(const f4*)(pw + (size_t)(q + 2) * sB);
    }

    // j = 0 columns: zeros
    #pragma unroll
    for (int k = 0; k < 4; ++k) {
        const int i = 4 * g + 1 + k;
        __builtin_nontemporal_store(z4, (f4*)(po + (size_t)(i * NCONN) * sB));
    }

    for (int j = 1; j < NCONN; ++j) {
        const int q = 3 * (j - 1);
        const f4 jx = *(const f4*)(pw + (size_t)(q + 0) * sB);
        const f4 jy = *(const f4*)(pw + (size_t)(q + 1) * sB);
        const f4 jz = *(const f4*)(pw + (size_t)(q + 2) * sB);
        #pragma unroll
        for (int k = 0; k < 4; ++k) {
            const int i = 4 * g + 1 + k;
            f4 ang;
            #pragma unroll
            for (int e = 0; e < 4; ++e) {
                float c = fmaf(ix[k][e], jx[e], fmaf(iy[k][e], jy[e], iz[k][e] * jz[e]));
                ang[e] = acos_poly(c);
            }
            __builtin_nontemporal_store(ang, (f4*)(po + (size_t)(i * NCONN + j) * sB));
        }
    }
}

// ============================ fallback: proven R2 kernel =====================
#define FTPB 512
#define FBPB 256
__global__ __launch_bounds__(FTPB, 4) void pv_fallback(const float* __restrict__ in,
                                                       float* __restrict__ out,
                                                       int B) {
    __shared__ float lds[FBPB * 64];
    const int tid = threadIdx.x;
    const long long blockBatch = (long long)blockIdx.x * FBPB;

    const long long gBase4 = blockBatch * 63 / 4;
    const long long totalF4 = ((long long)B * 63) >> 2;
    const float4* in4 = (const float4*)in;
    #pragma unroll
    for (int it = 0; it < 8; ++it) {
        int t4 = tid + it * FTPB;
        if (t4 < (FBPB * 63) / 4) {
            long long g4 = gBase4 + t4;
            if (g4 < totalF4) {
                float4 v = in4[g4];
                float vals[4] = {v.x, v.y, v.z, v.w};
                int f = 4 * t4;
                #pragma unroll
                for (int q = 0; q < 4; ++q) {
                    int f2 = f + q;
                    int r  = f2 / 63;
                    int c  = f2 - r * 63;
                    lds[r * 64 + ((c + (r >> 2)) & 63)] = vals[q];
                }
            }
        }
    }
    __syncthreads();

    if (tid < FBPB && blockBatch + tid < B) {
        float* row = lds + tid * 64;
        const int rot = tid >> 2;
        const float p0x = row[(0 + rot) & 63];
        const float p0y = row[(1 + rot) & 63];
        const float p0z = row[(2 + rot) & 63];
        #pragma unroll
        for (int e = 1; e < NCONN; ++e) {
            const int s0 = (3 * e + 0 + rot) & 63;
            const int s1 = (3 * e + 1 + rot) & 63;
            const int s2 = (3 * e + 2 + rot) & 63;
            float vx = row[s0] - p0x;
            float vy = row[s1] - p0y;
            float vz = row[s2] - p0z;
            float d  = fmaf(vx, vx, fmaf(vy, vy, vz * vz));
            float rr = rsqrtf(d);
            row[s0] = vx * rr;
            row[s1] = vy * rr;
            row[s2] = vz * rr;
        }
    }
    __syncthreads();

    const int l = tid & 63;
    const int w = tid >> 6;
    const int rowb = 4 * l;
    const long long remLL = B - blockBatch;
    const int rem = (int)(remLL < FBPB ? remLL : (long long)FBPB);
    const bool fullv = (rowb + 4 <= rem);
    float* op = out + blockBatch + rowb;
    const size_t sB = (size_t)B;

    {
        const f4 z4 = {0.f, 0.f, 0.f, 0.f};
        for (int idx = w; idx < 41; idx += 8) {
            const int p = (idx < 21) ? idx : (idx - 20) * NCONN;
            float* dst = op + (size_t)p * sB;
            if (fullv) __builtin_nontemporal_store(z4, (f4*)dst);
            else for (int k = 0; rowb + k < rem; ++k) dst[k] = 0.0f;
        }
    }

    for (int idx = w; idx < 400; idx += 8) {
        const int i = idx / 20 + 1;
        const int j = idx - (i - 1) * 20 + 1;
        f4 ang;
        #pragma unroll
        for (int k = 0; k < 4; ++k) {
            const float* row = lds + (rowb + k) * 64;
            const float uix = row[(3 * i + 0 + l) & 63];
            const float uiy = row[(3 * i + 1 + l) & 63];
            const float uiz = row[(3 * i + 2 + l) & 63];
            const float ujx = row[(3 * j + 0 + l) & 63];
            const float ujy = row[(3 * j + 1 + l) & 63];
            const float ujz = row[(3 * j + 2 + l) & 63];
            ang[k] = acos_poly(fmaf(uix, ujx, fmaf(uiy, ujy, uiz * ujz)));
        }
        float* dst = op + (size_t)(i * NCONN + j) * sB;
        if (fullv) __builtin_nontemporal_store(ang, (f4*)dst);
        else for (int k = 0; rowb + k < rem; ++k) dst[k] = ang[k];
    }
}

extern "C" void kernel_launch(void* const* d_in, const int* in_sizes, int n_in,
                              void* d_out, int out_size, void* d_ws, size_t ws_size,
                              hipStream_t stream) {
    const float* in = (const float*)d_in[0];
    float* out = (float*)d_out;
    const int B = in_sizes[0] / (NCONN * 3);   // 262144
    const size_t needWS = (size_t)60 * (size_t)B * sizeof(float);   // 62.9 MB

    if (ws_size >= needWS && (B % 1024) == 0) {
        float* ws = (float*)d_ws;
        hipLaunchKernelGGL(k1_planes, dim3(B / 256), dim3(256), 0, stream, in, ws, B);
        const int NS = B >> 10;                // 256 spans
        hipLaunchKernelGGL(k2_sweep, dim3(6 * NS), dim3(256), 0, stream, ws, out, B);
    } else {
        const int grid = (B + FBPB - 1) / FBPB;
        hipLaunchKernelGGL(pv_fallback, dim3(grid), dim3(FTPB), 0, stream, in, out, B);
    }
}